// Round 3
// baseline (1039.470 us; speedup 1.0000x reference)
//
#include <hip/hip_runtime.h>
#include <math.h>

#define BB 4
#define CCH 128
#define HH 384
#define WW 384

constexpr int TILE_X = 64;
constexpr int TILE_Y = 8;
constexpr int CC = 8;               // channels per staged chunk
constexpr int NCHUNK = CCH / CC;    // 16
constexpr int ROWS = TILE_Y + 2;    // 10 (rows y0 .. y0+9; fwd shifts only need dy>=0)
constexpr int STR  = 72;            // floats per stage row; col l <-> gx = x0-4+l
constexpr int GR   = 18;            // float4 groups per row
constexpr int NVEC = CC * ROWS * GR;  // 1440 float4 per chunk
constexpr int NLD  = 12;            // ceil(1440/128)
constexpr int NSTR = 76;            // norm tile stride
#define EPSQ 1e-8f

// 12 forward shifts: (0,1),(0,2),(1,-2..2),(2,-2..2). Each unordered pair {p,q}
// visited once with weight sel(p)+sel(q) == reference's 24 directed shifts.
// Clamped staging addresses only affect don't-care values (pairs touching them
// have weight 0 because sel requires the 2-pixel interior margin).

__global__ __launch_bounds__(128, 3)
void ctx_main(const float* __restrict__ er, const int* __restrict__ seg,
              const int* __restrict__ gt, float* __restrict__ Ssum,
              int* __restrict__ cntArr, int* __restrict__ bndArr)
{
    __shared__ __align__(16) float stage[CC * ROWS * STR];   // 23040 B
    __shared__ __align__(16) float normArr[ROWS * NSTR];     //  3040 B

    const int tx  = threadIdx.x;            // 0..15 (x groups of 4 px)
    const int ty  = threadIdx.y;            // 0..7  (rows)
    const int tid = ty * 16 + tx;
    const int x0  = blockIdx.x * TILE_X;
    const int y0  = blockIdx.y * TILE_Y;
    const int b   = blockIdx.z;

    // ---- precompute staging source offsets (reused across all 16 chunks) ----
    int srcOff[NLD];
    #pragma unroll
    for (int j = 0; j < NLD; ++j) {
        int id = tid + 128 * j; if (id > NVEC - 1) id = NVEC - 1;
        int c   = id / (ROWS * GR);
        int rem = id - c * (ROWS * GR);
        int r   = rem / GR;
        int g   = rem - r * GR;
        int gy  = y0 + r; if (gy > HH - 1) gy = HH - 1;
        int gx  = x0 - 4 + 4 * g;
        gx = min(max(gx, 0), WW - 4);
        srcOff[j] = (c * HH + gy) * WW + gx;
    }

    // ---- halo-norm pixel assignment (168: rows 8,9 cols 2..69; rows 0..7 cols 2,3,68,69) ----
    int hr[2] = {-1, -1}, hc[2] = {0, 0};
    #pragma unroll
    for (int k = 0; k < 2; ++k) {
        int h = tid + 128 * k;
        if (h < 136) { hr[k] = TILE_Y + h / 68; hc[k] = 2 + h % 68; }
        else if (h < 168) {
            int t = h - 136;
            hr[k] = t >> 2;
            int j = t & 3;
            hc[k] = (j < 2) ? (2 + j) : (66 + j);   // 2,3,68,69
        }
    }

    float acc[12][4];
    #pragma unroll
    for (int s = 0; s < 12; ++s)
        #pragma unroll
        for (int i = 0; i < 4; ++i) acc[s][i] = 0.f;
    float nrm[4] = {0.f, 0.f, 0.f, 0.f};
    float haloN[2] = {0.f, 0.f};

    const float* erB = er + (size_t)b * CCH * HH * WW;

    // ---- prologue: prefetch chunk 0 into registers ----
    float4 pre[NLD];
    #pragma unroll
    for (int j = 0; j < NLD; ++j)
        pre[j] = *(const float4*)(erB + srcOff[j]);

    for (int chunk = 0; chunk < NCHUNK; ++chunk) {
        __syncthreads();   // previous compute's LDS reads done; pre[] arrivals drained by store deps
        // ---- write prefetched registers -> LDS (conflict-free b128, lane-linear) ----
        #pragma unroll
        for (int j = 0; j < NLD; ++j) {
            int id = tid + 128 * j;
            bool ok = (j < NLD - 1) || (id < NVEC);
            if (id > NVEC - 1) id = NVEC - 1;
            if (ok) *(float4*)&stage[4 * id] = pre[j];
        }
        __syncthreads();
        // ---- issue next chunk's loads now; they fly under this chunk's compute ----
        if (chunk + 1 < NCHUNK) {
            const float* erN = erB + (size_t)(chunk + 1) * CC * HH * WW;
            #pragma unroll
            for (int j = 0; j < NLD; ++j)
                pre[j] = *(const float4*)(erN + srcOff[j]);
        }

        // ---- accumulate dots (12 fwd shifts) + own norms; aligned b128 reads ----
        #pragma unroll
        for (int c = 0; c < CC; ++c) {
            const float* rp = &stage[(c * ROWS + ty) * STR + 4 * tx];
            float L0[12], L1[12], L2[12];
            #pragma unroll
            for (int jj = 0; jj < 3; ++jj) {
                *(float4*)&L0[4 * jj] = *(const float4*)(rp + 4 * jj);
                *(float4*)&L1[4 * jj] = *(const float4*)(rp + STR + 4 * jj);
                *(float4*)&L2[4 * jj] = *(const float4*)(rp + 2 * STR + 4 * jj);
            }
            #pragma unroll
            for (int i = 0; i < 4; ++i) {
                float f = L0[4 + i];
                nrm[i]    = fmaf(f, f,         nrm[i]);
                acc[0][i] = fmaf(f, L0[5 + i], acc[0][i]);   // (0,+1)
                acc[1][i] = fmaf(f, L0[6 + i], acc[1][i]);   // (0,+2)
                #pragma unroll
                for (int d = 0; d < 5; ++d) {                // dx = d-2
                    acc[2 + d][i] = fmaf(f, L1[2 + i + d], acc[2 + d][i]); // dy=1
                    acc[7 + d][i] = fmaf(f, L2[2 + i + d], acc[7 + d][i]); // dy=2
                }
            }
        }
        // ---- halo norm partials (from LDS) ----
        #pragma unroll
        for (int k = 0; k < 2; ++k) if (hr[k] >= 0) {
            #pragma unroll
            for (int c = 0; c < CC; ++c) {
                float v = stage[(c * ROWS + hr[k]) * STR + hc[k]];
                haloN[k] = fmaf(v, v, haloN[k]);
            }
        }
    }

    __syncthreads();   // all compute reads done before stage is overwritten with labels

    // ---- build packed label/mask tile (reuse stage LDS) + norm tile ----
    int* pkT = (int*)stage;
    for (int it = tid; it < ROWS * STR; it += 128) {
        int r = it / STR, a = it - r * STR;
        int gy = y0 + r;
        int gx = x0 - 4 + a;
        int pk = 0;
        if (gy < HH && gx >= 0 && gx < WW) {
            int g   = gt[((size_t)b * HH + gy) * WW + gx];
            int gb  = (g == 255) ? 0 : g;
            int s0v = seg[(((size_t)b * 2 + 0) * HH + gy) * WW + gx];
            int s1v = seg[(((size_t)b * 2 + 1) * HH + gy) * WW + gx];
            int s1c = (s1v == 255) ? 0 : s1v;
            bool bnd   = (gb * s1c) > 0;
            bool inter = (gy >= 2 && gy <= HH - 3 && gx >= 2 && gx <= WW - 3);
            pk = (bnd ? 1 : 0) | ((bnd && inter) ? 2 : 0)
               | ((s0v & 255) << 8) | ((s1v & 255) << 16);
        }
        pkT[it] = pk;
    }
    #pragma unroll
    for (int i = 0; i < 4; ++i)
        normArr[ty * NSTR + 4 * tx + 4 + i] = sqrtf(nrm[i]);
    #pragma unroll
    for (int k = 0; k < 2; ++k) if (hr[k] >= 0)
        normArr[hr[k] * NSTR + hc[k]] = sqrtf(haloN[k]);
    __syncthreads();

    // ---- pair epilogue (12-wide windows, indices 2..9 used) ----
    const float* nr = &normArr[ty * NSTR + 4 * tx];
    const int*   pr = &pkT[ty * STR + 4 * tx];
    float n0[12], n1[12], n2[12];
    int   p0[12], p1[12], p2[12];
    #pragma unroll
    for (int jj = 0; jj < 3; ++jj) {
        *(float4*)&n0[4 * jj] = *(const float4*)(nr + 4 * jj);
        *(float4*)&n1[4 * jj] = *(const float4*)(nr + NSTR + 4 * jj);
        *(float4*)&n2[4 * jj] = *(const float4*)(nr + 2 * NSTR + 4 * jj);
        *(int4*)&p0[4 * jj] = *(const int4*)(pr + 4 * jj);
        *(int4*)&p1[4 * jj] = *(const int4*)(pr + STR + 4 * jj);
        *(int4*)&p2[4 * jj] = *(const int4*)(pr + 2 * STR + 4 * jj);
    }

    float Sth = 0.f; int cth = 0, bth = 0;
    #pragma unroll
    for (int i = 0; i < 4; ++i) {
        int pkP  = p0[4 + i];
        int selP = (pkP >> 1) & 1;
        cth += selP;
        bth += pkP & 1;
        float nP = fmaxf(n0[4 + i], EPSQ);
        auto doPair = [&](float dot, int pkQ, float nQv) {
            int w = selP + ((pkQ >> 1) & 1);
            if (w) {
                float lab = (float)(((pkP >> 8) & 255) * ((pkQ >> 8) & 255)
                                  + ((pkP >> 16) & 255) * ((pkQ >> 16) & 255));
                float cs = dot / (nP * fmaxf(nQv, EPSQ));
                float d  = cs - lab;
                Sth = fmaf((float)w * d, d, Sth);
            }
        };
        doPair(acc[0][i], p0[5 + i], n0[5 + i]);
        doPair(acc[1][i], p0[6 + i], n0[6 + i]);
        #pragma unroll
        for (int d2 = 0; d2 < 5; ++d2) {
            doPair(acc[2 + d2][i], p1[2 + i + d2], n1[2 + i + d2]);
            doPair(acc[7 + d2][i], p2[2 + i + d2], n2[2 + i + d2]);
        }
    }

    // ---- reduce + atomics ----
    #pragma unroll
    for (int off = 32; off > 0; off >>= 1) {
        Sth += __shfl_down(Sth, off);
        cth += __shfl_down(cth, off);
        bth += __shfl_down(bth, off);
    }
    if ((tid & 63) == 0) {
        atomicAdd(&Ssum[b], Sth);
        atomicAdd(&cntArr[b], cth);
        atomicAdd(&bndArr[b], bth);
    }
}

__global__ void ctx_init(float* S, int* cnt, int* bnd) {
    int t = threadIdx.x;
    if (t < BB) { S[t] = 0.f; cnt[t] = 0; bnd[t] = 0; }
}

__global__ void ctx_finalize(const float* __restrict__ S, const int* __restrict__ cnt,
                             const int* __restrict__ bnd, float* __restrict__ out) {
    if (threadIdx.x == 0 && blockIdx.x == 0) {
        float tot = 0.f, nv = 0.f;
        for (int b = 0; b < BB; ++b) {
            if (bnd[b] >= 1) {
                float c = fmaxf((float)cnt[b], 1.f);
                tot += S[b] / (24.f * c);
                nv  += 1.f;
            }
        }
        tot = tot / fmaxf(nv, 1.f);
        if (isnan(tot)) tot = 0.f;
        out[0] = tot;
    }
}

extern "C" void kernel_launch(void* const* d_in, const int* in_sizes, int n_in,
                              void* d_out, int out_size, void* d_ws, size_t ws_size,
                              hipStream_t stream) {
    const float* er = (const float*)d_in[0];
    const int* seg  = (const int*)d_in[1];
    const int* gt   = (const int*)d_in[2];
    float* out = (float*)d_out;

    float* S   = (float*)d_ws;
    int*   cnt = (int*)d_ws + BB;
    int*   bnd = (int*)d_ws + 2 * BB;

    ctx_init<<<1, 64, 0, stream>>>(S, cnt, bnd);
    dim3 grid(WW / TILE_X, HH / TILE_Y, BB);
    dim3 block(16, 8);
    ctx_main<<<grid, block, 0, stream>>>(er, seg, gt, S, cnt, bnd);
    ctx_finalize<<<1, 64, 0, stream>>>(S, cnt, bnd, out);
}

// Round 4
// 529.245 us; speedup vs baseline: 1.9641x; 1.9641x over previous
//
#include <hip/hip_runtime.h>
#include <math.h>

#define BB 4
#define CCH 128
#define HH 384
#define WW 384

constexpr int TILE_X = 64;
constexpr int TILE_Y = 16;
constexpr int CC = 4;               // channels per staged chunk
constexpr int NCHUNK = CCH / CC;    // 32
constexpr int ROWS = TILE_Y + 2;    // 18 (rows y0 .. y0+17; fwd shifts need dy>=0)
constexpr int STR  = 72;            // floats per stage row; col l <-> gx = x0-4+l
constexpr int GR   = 18;            // float4 groups per row
constexpr int NVEC = CC * ROWS * GR;  // 1296 float4 per chunk
constexpr int NLD  = 6;             // ceil(1296/256)
constexpr int NSTR = 76;            // norm tile stride
#define EPSQ 1e-8f

// 12 forward shifts: (0,1),(0,2),(1,-2..2),(2,-2..2). Each unordered pair {p,q}
// visited once with weight sel(p)+sel(q) == reference's 24 directed shifts.
// Clamped staging addresses only affect don't-care values (pairs touching them
// have weight 0 because sel requires the 2-pixel interior margin).
// Double-buffered global_load_lds: chunk k+1's loads are issued right after the
// barrier that drains chunk k's, so they fly under chunk k's compute.

__global__ __launch_bounds__(256, 3)
void ctx_main(const float* __restrict__ er, const int* __restrict__ seg,
              const int* __restrict__ gt, float* __restrict__ Ssum,
              int* __restrict__ cntArr, int* __restrict__ bndArr)
{
    __shared__ __align__(16) float buf0[CC * ROWS * STR];   // 20736 B
    __shared__ __align__(16) float buf1[CC * ROWS * STR];   // 20736 B
    __shared__ __align__(16) float normArr[ROWS * NSTR];    //  5472 B

    const int tx  = threadIdx.x;            // 0..15 (x groups of 4 px)
    const int ty  = threadIdx.y;            // 0..15 (rows)
    const int tid = ty * 16 + tx;
    const int x0  = blockIdx.x * TILE_X;
    const int y0  = blockIdx.y * TILE_Y;
    const int b   = blockIdx.z;

    // ---- staging source offsets (within a CC-channel slab), computed once ----
    int srcOff[NLD];
    #pragma unroll
    for (int j = 0; j < NLD; ++j) {
        int id = tid + 256 * j; if (id > NVEC - 1) id = NVEC - 1;
        int c   = id / (ROWS * GR);
        int rem = id - c * (ROWS * GR);
        int r   = rem / GR;
        int g   = rem - r * GR;
        int gy  = y0 + r; if (gy > HH - 1) gy = HH - 1;
        int gx  = x0 - 4 + 4 * g;
        gx = min(max(gx, 0), WW - 4);
        srcOff[j] = (c * HH + gy) * WW + gx;
    }

    // ---- halo-norm pixel (200: rows 16,17 cols 2..69; rows 0..15 cols 2,3,68,69) ----
    int hr = -1, hc = 0;
    if (tid < 136) { hr = TILE_Y + tid / 68; hc = 2 + tid % 68; }
    else if (tid < 200) {
        int t = tid - 136;
        hr = t >> 2;
        int j = t & 3;
        hc = (j < 2) ? (2 + j) : (66 + j);   // 2,3,68,69
    }

    float acc[12][4];
    #pragma unroll
    for (int s = 0; s < 12; ++s)
        #pragma unroll
        for (int i = 0; i < 4; ++i) acc[s][i] = 0.f;
    float nrm[4] = {0.f, 0.f, 0.f, 0.f};
    float haloN = 0.f;

    const float* erB = er + (size_t)b * CCH * HH * WW;

    auto issue = [&](int chunk, float* dst) {
        const float* erC = erB + (size_t)chunk * CC * HH * WW;
        #pragma unroll
        for (int j = 0; j < NLD; ++j) {
            int id = tid + 256 * j;
            if (j < NLD - 1 || id < NVEC) {
                __builtin_amdgcn_global_load_lds(
                    (const __attribute__((address_space(1))) void*)(erC + srcOff[j]),
                    (__attribute__((address_space(3))) void*)(dst + 4 * id),
                    16, 0, 0);
            }
        }
    };

    // ---- prologue: start chunk 0 ----
    issue(0, buf0);

    for (int chunk = 0; chunk < NCHUNK; ++chunk) {
        float* cur = (chunk & 1) ? buf1 : buf0;
        __syncthreads();   // drains chunk's loads (issued last iter, flew under compute)
        if (chunk + 1 < NCHUNK) issue(chunk + 1, (chunk & 1) ? buf0 : buf1);

        // ---- accumulate dots (12 fwd shifts) + own norms; aligned b128 reads ----
        #pragma unroll
        for (int c = 0; c < CC; ++c) {
            const float* rp = &cur[(c * ROWS + ty) * STR + 4 * tx];
            float L0[12], L1[12], L2[12];
            #pragma unroll
            for (int jj = 0; jj < 3; ++jj) {
                *(float4*)&L0[4 * jj] = *(const float4*)(rp + 4 * jj);
                *(float4*)&L1[4 * jj] = *(const float4*)(rp + STR + 4 * jj);
                *(float4*)&L2[4 * jj] = *(const float4*)(rp + 2 * STR + 4 * jj);
            }
            #pragma unroll
            for (int i = 0; i < 4; ++i) {
                float f = L0[4 + i];
                nrm[i]    = fmaf(f, f,         nrm[i]);
                acc[0][i] = fmaf(f, L0[5 + i], acc[0][i]);   // (0,+1)
                acc[1][i] = fmaf(f, L0[6 + i], acc[1][i]);   // (0,+2)
                #pragma unroll
                for (int d = 0; d < 5; ++d) {                // dx = d-2
                    acc[2 + d][i] = fmaf(f, L1[2 + i + d], acc[2 + d][i]); // dy=1
                    acc[7 + d][i] = fmaf(f, L2[2 + i + d], acc[7 + d][i]); // dy=2
                }
            }
        }
        // ---- halo norm partials (from cur) ----
        if (hr >= 0) {
            #pragma unroll
            for (int c = 0; c < CC; ++c) {
                float v = cur[(c * ROWS + hr) * STR + hc];
                haloN = fmaf(v, v, haloN);
            }
        }
    }

    __syncthreads();   // all compute reads done before buf0 is reused for labels

    // ---- build packed label/mask tile (reuse buf0) + norm tile ----
    int* pkT = (int*)buf0;
    for (int it = tid; it < ROWS * STR; it += 256) {
        int r = it / STR, a = it - r * STR;
        int gy = y0 + r;
        int gx = x0 - 4 + a;
        int pk = 0;
        if (gy < HH && gx >= 0 && gx < WW) {
            int g   = gt[((size_t)b * HH + gy) * WW + gx];
            int gb  = (g == 255) ? 0 : g;
            int s0v = seg[(((size_t)b * 2 + 0) * HH + gy) * WW + gx];
            int s1v = seg[(((size_t)b * 2 + 1) * HH + gy) * WW + gx];
            int s1c = (s1v == 255) ? 0 : s1v;
            bool bnd   = (gb * s1c) > 0;
            bool inter = (gy >= 2 && gy <= HH - 3 && gx >= 2 && gx <= WW - 3);
            pk = (bnd ? 1 : 0) | ((bnd && inter) ? 2 : 0)
               | ((s0v & 255) << 8) | ((s1v & 255) << 16);
        }
        pkT[it] = pk;
    }
    #pragma unroll
    for (int i = 0; i < 4; ++i)
        normArr[ty * NSTR + 4 * tx + 4 + i] = sqrtf(nrm[i]);
    if (hr >= 0) normArr[hr * NSTR + hc] = sqrtf(haloN);
    __syncthreads();

    // ---- pair epilogue (12-wide windows; own px at indices 4..7) ----
    const float* nr = &normArr[ty * NSTR + 4 * tx];
    const int*   pr = &pkT[ty * STR + 4 * tx];
    float n0[12], n1[12], n2[12];
    int   p0[12], p1[12], p2[12];
    #pragma unroll
    for (int jj = 0; jj < 3; ++jj) {
        *(float4*)&n0[4 * jj] = *(const float4*)(nr + 4 * jj);
        *(float4*)&n1[4 * jj] = *(const float4*)(nr + NSTR + 4 * jj);
        *(float4*)&n2[4 * jj] = *(const float4*)(nr + 2 * NSTR + 4 * jj);
        *(int4*)&p0[4 * jj] = *(const int4*)(pr + 4 * jj);
        *(int4*)&p1[4 * jj] = *(const int4*)(pr + STR + 4 * jj);
        *(int4*)&p2[4 * jj] = *(const int4*)(pr + 2 * STR + 4 * jj);
    }

    float Sth = 0.f; int cth = 0, bth = 0;
    #pragma unroll
    for (int i = 0; i < 4; ++i) {
        int pkP  = p0[4 + i];
        int selP = (pkP >> 1) & 1;
        cth += selP;
        bth += pkP & 1;
        float nP = fmaxf(n0[4 + i], EPSQ);
        auto doPair = [&](float dot, int pkQ, float nQv) {
            int w = selP + ((pkQ >> 1) & 1);
            if (w) {
                float lab = (float)(((pkP >> 8) & 255) * ((pkQ >> 8) & 255)
                                  + ((pkP >> 16) & 255) * ((pkQ >> 16) & 255));
                float cs = dot / (nP * fmaxf(nQv, EPSQ));
                float d  = cs - lab;
                Sth = fmaf((float)w * d, d, Sth);
            }
        };
        doPair(acc[0][i], p0[5 + i], n0[5 + i]);
        doPair(acc[1][i], p0[6 + i], n0[6 + i]);
        #pragma unroll
        for (int d2 = 0; d2 < 5; ++d2) {
            doPair(acc[2 + d2][i], p1[2 + i + d2], n1[2 + i + d2]);
            doPair(acc[7 + d2][i], p2[2 + i + d2], n2[2 + i + d2]);
        }
    }

    // ---- reduce + atomics (one per wave) ----
    #pragma unroll
    for (int off = 32; off > 0; off >>= 1) {
        Sth += __shfl_down(Sth, off);
        cth += __shfl_down(cth, off);
        bth += __shfl_down(bth, off);
    }
    if ((tid & 63) == 0) {
        atomicAdd(&Ssum[b], Sth);
        atomicAdd(&cntArr[b], cth);
        atomicAdd(&bndArr[b], bth);
    }
}

__global__ void ctx_init(float* S, int* cnt, int* bnd) {
    int t = threadIdx.x;
    if (t < BB) { S[t] = 0.f; cnt[t] = 0; bnd[t] = 0; }
}

__global__ void ctx_finalize(const float* __restrict__ S, const int* __restrict__ cnt,
                             const int* __restrict__ bnd, float* __restrict__ out) {
    if (threadIdx.x == 0 && blockIdx.x == 0) {
        float tot = 0.f, nv = 0.f;
        for (int b = 0; b < BB; ++b) {
            if (bnd[b] >= 1) {
                float c = fmaxf((float)cnt[b], 1.f);
                tot += S[b] / (24.f * c);
                nv  += 1.f;
            }
        }
        tot = tot / fmaxf(nv, 1.f);
        if (isnan(tot)) tot = 0.f;
        out[0] = tot;
    }
}

extern "C" void kernel_launch(void* const* d_in, const int* in_sizes, int n_in,
                              void* d_out, int out_size, void* d_ws, size_t ws_size,
                              hipStream_t stream) {
    const float* er = (const float*)d_in[0];
    const int* seg  = (const int*)d_in[1];
    const int* gt   = (const int*)d_in[2];
    float* out = (float*)d_out;

    float* S   = (float*)d_ws;
    int*   cnt = (int*)d_ws + BB;
    int*   bnd = (int*)d_ws + 2 * BB;

    ctx_init<<<1, 64, 0, stream>>>(S, cnt, bnd);
    dim3 grid(WW / TILE_X, HH / TILE_Y, BB);
    dim3 block(16, 16);
    ctx_main<<<grid, block, 0, stream>>>(er, seg, gt, S, cnt, bnd);
    ctx_finalize<<<1, 64, 0, stream>>>(S, cnt, bnd, out);
}